// Round 6
// baseline (438.031 us; speedup 1.0000x reference)
//
#include <hip/hip_runtime.h>

// ---------- types ----------
typedef __bf16 vbf8 __attribute__((ext_vector_type(8)));
typedef __bf16 vbf4 __attribute__((ext_vector_type(4)));
typedef unsigned short us8 __attribute__((ext_vector_type(8)));
typedef float f32x4 __attribute__((ext_vector_type(4)));
typedef float f32x4u __attribute__((ext_vector_type(4), aligned(4)));

// ---------- band-case helpers ----------
// Band layout at size H with e leading/trailing singles: bands
// 0..e-1 (rows 0..e-1), band e (rows e..H-1-e), bands e+1..2e (rows H-e..H-1).
__device__ __forceinline__ int caseof(int h, int H, int e) {
  if (h < 0 || h >= H) return -1;           // EDGE
  if (h < e) return h;
  if (h >= H - e) return h - (H - 1) + 2 * e;
  return e;
}
__device__ __forceinline__ int repof(int i, int H, int eo) {
  return (i <= eo) ? i : H - 1 - 2 * eo + i;
}

// ---------------------------------------------------------------------------
// setup: precompute MFMA weight fragments for the pillar net (see R5 notes).
// ---------------------------------------------------------------------------
__global__ void setup_kernel(const float* __restrict__ w1, const float* __restrict__ b1,
                             const float* __restrict__ s1, const float* __restrict__ t1,
                             const float* __restrict__ w2, const float* __restrict__ b2,
                             const float* __restrict__ s2, const float* __restrict__ t2,
                             __bf16* __restrict__ wfrag, float* __restrict__ be2f) {
  int l = threadIdx.x;                       // 0..63
  int s = l & 15, g = l >> 4;
#pragma unroll
  for (int m = 0; m < 4; ++m) {
    int c = 32 * (m & 1) + 8 * (s >> 2) + 4 * (m >> 1) + (s & 3);
#pragma unroll
    for (int e = 0; e < 8; ++e) {
      int k = g * 8 + e;
      float v = 0.f;
      if (k < 9)       v = w1[k * 64 + c] * s1[c];
      else if (k == 9) v = fmaf(b1[c], s1[c], t1[c]);
      wfrag[(m * 64 + l) * 8 + e] = (__bf16)v;
    }
    int co = s + 16 * m;
#pragma unroll
    for (int e = 0; e < 8; ++e) {
      int k = g * 8 + e;
      wfrag[((4 + m) * 64 + l) * 8 + e] = (__bf16)(w2[k * 64 + co] * s2[co]);
      wfrag[((8 + m) * 64 + l) * 8 + e] = (__bf16)(w2[(32 + k) * 64 + co] * s2[co]);
    }
    be2f[m * 64 + l] = fmaf(b2[co], s2[co], t2[co]);
  }
}

// ---------------------------------------------------------------------------
// weight transpose+convert, LDS-tiled: HWIO [tap][ci][co] f32 -> [tap][co][ci] bf16
// ---------------------------------------------------------------------------
__global__ __launch_bounds__(256) void convw_kernel(
    const float* __restrict__ k1, const float* __restrict__ k2,
    const float* __restrict__ k3, const float* __restrict__ k4,
    const float* __restrict__ k5, const float* __restrict__ k6,
    const float* __restrict__ kh, __bf16* __restrict__ wT) {
  __shared__ float tile[64][65];
  const int tCI[7]    = {64, 64, 64, 128, 128, 256, 256};
  const int tCO[7]    = {64, 64, 128, 128, 256, 256, 256};
  const int tOFF[7]   = {0, 36864, 73728, 147456, 294912, 589824, 1179648};
  const int tTILES[7] = {9, 9, 18, 36, 72, 144, 144};
  int bid = blockIdx.x;
  int ti = 0, acc = 0;
  while (ti < 6 && bid >= acc + tTILES[ti]) { acc += tTILES[ti]; ++ti; }
  int lt = bid - acc;
  int CI = tCI[ti], CO = tCO[ti];
  const float* src;
  if (ti == 0) src = k1; else if (ti == 1) src = k2; else if (ti == 2) src = k3;
  else if (ti == 3) src = k4; else if (ti == 4) src = k5; else if (ti == 5) src = k6;
  else src = kh;
  int cot = CO / 64, tpt = (CI / 64) * cot;
  int tap = lt / tpt; int r2 = lt - tap * tpt;
  int ci0 = (r2 / cot) * 64, co0 = (r2 % cot) * 64;
  const float* sp = src + (size_t)(tap * CI + ci0) * CO + co0;
  int t = threadIdx.x;
  int lr = t >> 6, lc = t & 63;
#pragma unroll
  for (int rr = 0; rr < 64; rr += 4)
    tile[rr + lr][lc] = sp[(size_t)(rr + lr) * CO + lc];
  __syncthreads();
  __bf16* dst = wT + tOFF[ti] + ((size_t)tap * CO + co0) * CI + ci0;
#pragma unroll
  for (int rr = 0; rr < 64; rr += 4)
    dst[(size_t)(rr + lr) * CI + lc] = (__bf16)tile[lc][rr + lr];
}

// ---------------------------------------------------------------------------
// Stage A: pillar feature net (unchanged from R5 — known-good, 118 us).
// ---------------------------------------------------------------------------
__global__ __launch_bounds__(256) void pillar_kernel(
    const float* __restrict__ pil, const int* __restrict__ npt,
    const __bf16* __restrict__ wfrag, const float* __restrict__ be2f,
    float* __restrict__ partial, int* __restrict__ pcnt)
{
  __shared__ float redf[4][64];
  __shared__ int redc[4];
  const int tid = threadIdx.x;
  const int wv = tid >> 6, lane = tid & 63;
  const int s = lane & 15, g = lane >> 4;
  const int wid = blockIdx.x * 4 + wv;       // 0..23999
  const int b = wid / 6000;
  const int p0 = (wid - b * 6000) * 2;

  vbf8 w1f[4], w2f0[4], w2f1[4];
  float be2[4];
#pragma unroll
  for (int m = 0; m < 4; ++m) {
    w1f[m]  = *(const vbf8*)(wfrag + ((0 + m) * 64 + lane) * 8);
    w2f0[m] = *(const vbf8*)(wfrag + ((4 + m) * 64 + lane) * 8);
    w2f1[m] = *(const vbf8*)(wfrag + ((8 + m) * 64 + lane) * 8);
    be2[m] = be2f[m * 64 + lane];
  }

  float fsum[4] = {0.f, 0.f, 0.f, 0.f};
  int cnt = 0;

  for (int i = 0; i < 2; ++i) {
    int pidx = b * 12000 + p0 + i;
    int np = npt[pidx];
    if (np <= 0) continue;     // wave-uniform
    ++cnt;
    float feat[4][4];
#pragma unroll
    for (int n = 0; n < 4; ++n)
#pragma unroll
      for (int r = 0; r < 4; ++r) feat[n][r] = 0.f;

    int ngrp = (np + 15) >> 4;
    const float* pbase = pil + (size_t)pidx * 900;
    for (int grp = 0; grp < ngrp; ++grp) {
      int pt = grp * 16 + s; pt = min(pt, 99);
      const float* ptp = pbase + pt * 9;
      f32x4u lo = *(const f32x4u*)ptp;
      f32x4u hi = *(const f32x4u*)(ptp + 4);
      float v8 = ptp[8];
      vbf8 b1f;
      b1f[0] = (__bf16)(g == 0 ? lo[0] : (g == 1 ? v8 : 0.f));
      b1f[1] = (__bf16)(g == 0 ? lo[1] : (g == 1 ? 1.0f : 0.f));
      b1f[2] = (__bf16)(g == 0 ? lo[2] : 0.f);
      b1f[3] = (__bf16)(g == 0 ? lo[3] : 0.f);
      b1f[4] = (__bf16)(g == 0 ? hi[0] : 0.f);
      b1f[5] = (__bf16)(g == 0 ? hi[1] : 0.f);
      b1f[6] = (__bf16)(g == 0 ? hi[2] : 0.f);
      b1f[7] = (__bf16)(g == 0 ? hi[3] : 0.f);

      const f32x4 z = {0.f, 0.f, 0.f, 0.f};
      f32x4 d1[4];
#pragma unroll
      for (int m = 0; m < 4; ++m)
        d1[m] = __builtin_amdgcn_mfma_f32_16x16x32_bf16(w1f[m], b1f, z, 0, 0, 0);

      vbf8 a2f0, a2f1;
#pragma unroll
      for (int r = 0; r < 4; ++r) {
        a2f0[r]     = (__bf16)fmaxf(d1[0][r], 0.f);
        a2f1[r]     = (__bf16)fmaxf(d1[1][r], 0.f);
        a2f0[4 + r] = (__bf16)fmaxf(d1[2][r], 0.f);
        a2f1[4 + r] = (__bf16)fmaxf(d1[3][r], 0.f);
      }

      f32x4 d2[4];
#pragma unroll
      for (int n = 0; n < 4; ++n) {
        f32x4 cb = {be2[n], be2[n], be2[n], be2[n]};
        d2[n] = __builtin_amdgcn_mfma_f32_16x16x32_bf16(a2f0, w2f0[n], cb, 0, 0, 0);
        d2[n] = __builtin_amdgcn_mfma_f32_16x16x32_bf16(a2f1, w2f1[n], d2[n], 0, 0, 0);
      }
      if (((grp + 1) << 4) <= np) {
#pragma unroll
        for (int n = 0; n < 4; ++n)
#pragma unroll
          for (int r = 0; r < 4; ++r) feat[n][r] = fmaxf(feat[n][r], d2[n][r]);
      } else {
#pragma unroll
        for (int n = 0; n < 4; ++n)
#pragma unroll
          for (int r = 0; r < 4; ++r) {
            float vv = (grp * 16 + 4 * g + r < np) ? d2[n][r] : 0.f;
            feat[n][r] = fmaxf(feat[n][r], vv);
          }
      }
    }
#pragma unroll
    for (int n = 0; n < 4; ++n) {
      float m = fmaxf(fmaxf(feat[n][0], feat[n][1]), fmaxf(feat[n][2], feat[n][3]));
      m = fmaxf(m, __shfl_xor(m, 16));
      m = fmaxf(m, __shfl_xor(m, 32));
      fsum[n] += m;
    }
  }
  if (g == 0) {
#pragma unroll
    for (int n = 0; n < 4; ++n) redf[wv][s + 16 * n] = fsum[n];
  }
  if (lane == 0) redc[wv] = cnt;
  __syncthreads();
  if (tid < 64) {
    float tot = redf[0][tid] + redf[1][tid] + redf[2][tid] + redf[3][tid];
    partial[blockIdx.x * 64 + tid] = tot;
    if (tid == 0) pcnt[blockIdx.x] = redc[0] + redc[1] + redc[2] + redc[3];
  }
}

// finish the mean + emit bf16 case-array X0 [1][1][4][64] + zero the zbuf page
__global__ void mean_kernel(const float* __restrict__ partial,
                            const int* __restrict__ pcnt,
                            float* __restrict__ mean, __bf16* __restrict__ x0,
                            __bf16* __restrict__ zbuf) {
  int b = blockIdx.x, t = threadIdx.x;
  if (b == 0) zbuf[t] = (__bf16)0.f;        // 256 bf16 zero page
  int c = t & 63, q = t >> 6;
  float sum = 0.f;
  for (int w = q; w < 1500; w += 4) sum += partial[(b * 1500 + w) * 64 + c];
  int cl = 0;
  for (int w = t; w < 1500; w += 256) cl += pcnt[b * 1500 + w];
  __shared__ float sh[256];
  __shared__ int shc[256];
  sh[t] = sum; shc[t] = cl;
  __syncthreads();
  for (int o = 128; o > 0; o >>= 1) {
    if (t < o) shc[t] += shc[t + o];
    __syncthreads();
  }
  if (t < 64) {
    float tot = sh[t] + sh[t + 64] + sh[t + 128] + sh[t + 192];
    float mv = tot / (float)(shc[0] > 0 ? shc[0] : 1);
    mean[b * 64 + t] = mv;
    x0[b * 64 + t] = (__bf16)mv;
  }
}

// ---------------------------------------------------------------------------
// Case-grid 3x3 conv (bf16 MFMA, full K per wave, fused BN/bias + ReLU).
// In: xin[NBI][NBI][4][CI] bf16 case values (band param EIN at size H).
// Out: [NBO][NBO][4][CO] (bf16, or f32 for the head-conv output).
// A row m = ((bh*NBO+bw)*4+b); EDGE taps read the zero page.
// ---------------------------------------------------------------------------
template <int CI, int CO, int H, int EIN, bool HAS_BN, bool OUT_F32>
__global__ __launch_bounds__(256) void caseconv_kernel(
    const __bf16* __restrict__ xin, const __bf16* __restrict__ wt,
    const float* __restrict__ cb, const float* __restrict__ cs,
    const float* __restrict__ ct, __bf16* __restrict__ yout,
    float* __restrict__ yf32, const __bf16* __restrict__ zbuf)
{
  constexpr int EOUT = EIN + 1;
  constexpr int NBI = 2 * EIN + 1;
  constexpr int NBO = 2 * EOUT + 1;
  constexpr int M = NBO * NBO * 4;
  constexpr int NT = CO / 64;
  constexpr int KC = CI / 32;
  constexpr int MT = (M + 31) / 32;
  const int tid = threadIdx.x, wv = tid >> 6, lane = tid & 63;
  const int s = lane & 15, g = lane >> 4;
  const int task = blockIdx.x * 4 + wv;
  if (task >= MT * NT) return;
  const int nt = task % NT, mt = task / NT;

  const __bf16* pa[2][9];
#pragma unroll
  for (int mf = 0; mf < 2; ++mf) {
    int m = mt * 32 + mf * 16 + s; if (m >= M) m = M - 1;
    int b = m & 3, q = m >> 2;
    int bw = q % NBO, bh = q / NBO;
    int reph = repof(bh, H, EOUT), repw = repof(bw, H, EOUT);
#pragma unroll
    for (int dh = 0; dh < 3; ++dh)
#pragma unroll
      for (int dw = 0; dw < 3; ++dw) {
        int jh = caseof(reph + dh - 1, H, EIN);
        int jw = caseof(repw + dw - 1, H, EIN);
        bool v = (jh >= 0) && (jw >= 0);
        pa[mf][dh * 3 + dw] =
            v ? xin + (size_t)((jh * NBI + jw) * 4 + b) * CI : zbuf;
      }
  }

  f32x4 acc[2][4];
#pragma unroll
  for (int mf = 0; mf < 2; ++mf)
#pragma unroll
    for (int nf = 0; nf < 4; ++nf) acc[mf][nf] = (f32x4){0.f, 0.f, 0.f, 0.f};

#pragma unroll
  for (int tap = 0; tap < 9; ++tap) {
    const __bf16* wtap = wt + ((size_t)tap * CO + nt * 64) * CI + 8 * g;
#pragma unroll
    for (int ck = 0; ck < KC; ++ck) {
      vbf8 a0 = *(const vbf8*)(pa[0][tap] + ck * 32 + 8 * g);
      vbf8 a1 = *(const vbf8*)(pa[1][tap] + ck * 32 + 8 * g);
#pragma unroll
      for (int nf = 0; nf < 4; ++nf) {
        vbf8 bb = *(const vbf8*)(wtap + (size_t)(nf * 16 + s) * CI + ck * 32);
        acc[0][nf] = __builtin_amdgcn_mfma_f32_16x16x32_bf16(a0, bb, acc[0][nf], 0, 0, 0);
        acc[1][nf] = __builtin_amdgcn_mfma_f32_16x16x32_bf16(a1, bb, acc[1][nf], 0, 0, 0);
      }
    }
  }

#pragma unroll
  for (int nf = 0; nf < 4; ++nf) {
    int co = nt * 64 + nf * 16 + s;
    float sc, sh;
    if (HAS_BN) { sc = cs[co]; sh = fmaf(cb[co], sc, ct[co]); }
    else        { sc = 1.f;    sh = cb[co]; }
#pragma unroll
    for (int mf = 0; mf < 2; ++mf)
#pragma unroll
      for (int r = 0; r < 4; ++r) {
        int m = mt * 32 + mf * 16 + 4 * g + r;
        if (m < M) {
          float v = fmaxf(fmaf(acc[mf][nf][r], sc, sh), 0.f);
          if constexpr (OUT_F32) yf32[(size_t)m * CO + co] = v;
          else                   yout[(size_t)m * CO + co] = (__bf16)v;
        }
      }
  }
}

// ---------------------------------------------------------------------------
// Case-grid 2x2 max pool (input band param EIN at size 2*HOUT).
// ---------------------------------------------------------------------------
template <int C, int HOUT, int EIN>
__global__ void casepool_kernel(const __bf16* __restrict__ xin,
                                __bf16* __restrict__ yout) {
  constexpr int EOUT = (EIN + 1) / 2;
  constexpr int NBI = 2 * EIN + 1;
  constexpr int NBO = 2 * EOUT + 1;
  constexpr int C8 = C / 8;
  int idx = blockIdx.x * 256 + threadIdx.x;
  if (idx >= NBO * NBO * 4 * C8) return;
  int c8 = idx % C8; int rest = idx / C8;
  int b = rest & 3; int pos = rest >> 2;
  int iw = pos % NBO, ih = pos / NBO;
  int rh = repof(ih, HOUT, EOUT), rw = repof(iw, HOUT, EOUT);
  int h0 = caseof(2 * rh, 2 * HOUT, EIN), h1 = caseof(2 * rh + 1, 2 * HOUT, EIN);
  int w0 = caseof(2 * rw, 2 * HOUT, EIN), w1 = caseof(2 * rw + 1, 2 * HOUT, EIN);
  const unsigned short* xp = (const unsigned short*)xin;
  us8 v00 = *(const us8*)(xp + (size_t)((h0 * NBI + w0) * 4 + b) * C + c8 * 8);
  us8 v01 = *(const us8*)(xp + (size_t)((h0 * NBI + w1) * 4 + b) * C + c8 * 8);
  us8 v10 = *(const us8*)(xp + (size_t)((h1 * NBI + w0) * 4 + b) * C + c8 * 8);
  us8 v11 = *(const us8*)(xp + (size_t)((h1 * NBI + w1) * 4 + b) * C + c8 * 8);
  us8 o;
#pragma unroll
  for (int e = 0; e < 8; ++e) {
    unsigned short a = v00[e] > v01[e] ? v00[e] : v01[e];
    unsigned short c = v10[e] > v11[e] ? v10[e] : v11[e];
    o[e] = a > c ? a : c;
  }
  *(us8*)((unsigned short*)yout + (size_t)((ih * NBO + iw) * 4 + b) * C + c8 * 8) = o;
}

// 1x1 conv 256 -> 10 + bias over the 11x11 case grid, fp32
__global__ void head2c_kernel(const float* __restrict__ x, const float* __restrict__ wk,
                              const float* __restrict__ bias, float* __restrict__ y) {
  int idx = blockIdx.x * 256 + threadIdx.x;
  if (idx >= 121 * 4 * 16) return;
  int co = idx & 15;
  if (co >= 10) return;
  int q = idx >> 4;
  const float* xr = x + (size_t)q * 256;     // q = pos*4 + b
  float acc = 0.f;
#pragma unroll 4
  for (int ci = 0; ci < 256; ci += 4) {
    float4 in4 = *(const float4*)(xr + ci);
    acc = fmaf(in4.x, wk[(ci + 0) * 10 + co], acc);
    acc = fmaf(in4.y, wk[(ci + 1) * 10 + co], acc);
    acc = fmaf(in4.z, wk[(ci + 2) * 10 + co], acc);
    acc = fmaf(in4.w, wk[(ci + 3) * 10 + co], acc);
  }
  y[(size_t)q * 10 + co] = acc + bias[co];
}

// scatter case-grid head output -> full 27x31 NCHW output
__global__ void scatter_kernel(const float* __restrict__ y, float* __restrict__ out) {
  int idx = blockIdx.x * 256 + threadIdx.x;
  if (idx >= 4 * 10 * 27 * 31) return;
  int c = idx % 31;
  int r = (idx / 31) % 27;
  int ch = (idx / (31 * 27)) % 10;
  int b = idx / (31 * 27 * 10);
  int rr = (r <= 7) ? r : ((r >= 20) ? r - 11 : 7);
  int cc = (c <= 7) ? c : ((c >= 24) ? c - 15 : 7);
  int ph = caseof(rr, 16, 5), pw = caseof(cc, 16, 5);
  out[idx] = y[(size_t)(((ph * 11 + pw) * 4 + b)) * 10 + ch];
}

// ---------------------------------------------------------------------------
extern "C" void kernel_launch(void* const* d_in, const int* in_sizes, int n_in,
                              void* d_out, int out_size, void* d_ws, size_t ws_size,
                              hipStream_t stream) {
  (void)in_sizes; (void)n_in; (void)out_size; (void)ws_size;
  const float* pillars = (const float*)d_in[0];
  const float* w1 = (const float*)d_in[1];
  const float* b1 = (const float*)d_in[2];
  const float* s1 = (const float*)d_in[3];
  const float* t1 = (const float*)d_in[4];
  const float* w2 = (const float*)d_in[5];
  const float* b2 = (const float*)d_in[6];
  const float* s2 = (const float*)d_in[7];
  const float* t2 = (const float*)d_in[8];
  const float* ck[6], *cbv[6], *csv[6], *ctv[6];
  for (int i = 0; i < 6; ++i) {
    ck[i]  = (const float*)d_in[9 + i * 4];
    cbv[i] = (const float*)d_in[10 + i * 4];
    csv[i] = (const float*)d_in[11 + i * 4];
    ctv[i] = (const float*)d_in[12 + i * 4];
  }
  const float* hk1 = (const float*)d_in[33];
  const float* hb1 = (const float*)d_in[34];
  const float* hk2 = (const float*)d_in[35];
  const float* hb2 = (const float*)d_in[36];
  const int* num_points = (const int*)d_in[37];
  float* out = (float*)d_out;

  // ---- ws layout ----
  char* wsb = (char*)d_ws;
  size_t off = 0;
  auto alloc = [&](size_t n) { char* p = wsb + off; off = (off + n + 255) & ~(size_t)255; return p; };
  float*  ppart = (float*)alloc(1536000);
  int*    pcnt  = (int*)alloc(24000);
  float*  mean  = (float*)alloc(1024);
  __bf16* wfrag = (__bf16*)alloc(12288);
  float*  be2f  = (float*)alloc(1024);
  __bf16* wT    = (__bf16*)alloc(3538944);
  __bf16* zbuf  = (__bf16*)alloc(512);
  __bf16* X0    = (__bf16*)alloc(512);       // 1x1x4x64
  __bf16* X1    = (__bf16*)alloc(4608);      // 3x3x4x64
  __bf16* X2    = (__bf16*)alloc(12800);     // 5x5x4x64
  __bf16* P1    = (__bf16*)alloc(4608);      // 3x3x4x64
  __bf16* X3    = (__bf16*)alloc(25600);     // 5x5x4x128
  __bf16* X4    = (__bf16*)alloc(50176);     // 7x7x4x128
  __bf16* P2    = (__bf16*)alloc(25600);     // 5x5x4x128
  __bf16* X5    = (__bf16*)alloc(100352);    // 7x7x4x256
  __bf16* X6    = (__bf16*)alloc(165888);    // 9x9x4x256
  float*  XH    = (float*)alloc(495616);     // 11x11x4x256 f32
  float*  h2out = (float*)alloc(19360);      // 11x11x4x10

  __bf16* wt1 = wT + 0;       __bf16* wt2 = wT + 36864;
  __bf16* wt3 = wT + 73728;   __bf16* wt4 = wT + 147456;
  __bf16* wt5 = wT + 294912;  __bf16* wt6 = wT + 589824;
  __bf16* wth = wT + 1179648;

  setup_kernel<<<1, 64, 0, stream>>>(w1, b1, s1, t1, w2, b2, s2, t2, wfrag, be2f);
  convw_kernel<<<432, 256, 0, stream>>>(ck[0], ck[1], ck[2], ck[3], ck[4], ck[5],
                                        hk1, wT);
  pillar_kernel<<<6000, 256, 0, stream>>>(pillars, num_points, wfrag, be2f,
                                          ppart, pcnt);
  mean_kernel<<<4, 256, 0, stream>>>(ppart, pcnt, mean, X0, zbuf);

  // backbone on the case grid
  caseconv_kernel<64, 64, 64, 0, true, false><<<1, 256, 0, stream>>>(
      X0, wt1, cbv[0], csv[0], ctv[0], X1, nullptr, zbuf);
  caseconv_kernel<64, 64, 64, 1, true, false><<<1, 256, 0, stream>>>(
      X1, wt2, cbv[1], csv[1], ctv[1], X2, nullptr, zbuf);
  casepool_kernel<64, 32, 2><<<2, 256, 0, stream>>>(X2, P1);
  caseconv_kernel<64, 128, 32, 1, true, false><<<2, 256, 0, stream>>>(
      P1, wt3, cbv[2], csv[2], ctv[2], X3, nullptr, zbuf);
  caseconv_kernel<128, 128, 32, 2, true, false><<<4, 256, 0, stream>>>(
      X3, wt4, cbv[3], csv[3], ctv[3], X4, nullptr, zbuf);
  casepool_kernel<128, 16, 3><<<7, 256, 0, stream>>>(X4, P2);
  caseconv_kernel<128, 256, 16, 2, true, false><<<7, 256, 0, stream>>>(
      P2, wt5, cbv[4], csv[4], ctv[4], X5, nullptr, zbuf);
  caseconv_kernel<256, 256, 16, 3, true, false><<<11, 256, 0, stream>>>(
      X5, wt6, cbv[5], csv[5], ctv[5], X6, nullptr, zbuf);
  caseconv_kernel<256, 256, 16, 4, false, true><<<16, 256, 0, stream>>>(
      X6, wth, hb1, nullptr, nullptr, nullptr, XH, zbuf);

  head2c_kernel<<<31, 256, 0, stream>>>(XH, hk2, hb2, h2out);
  scatter_kernel<<<131, 256, 0, stream>>>(h2out, out);
}

// Round 7
// 368.562 us; speedup vs baseline: 1.1885x; 1.1885x over previous
//
#include <hip/hip_runtime.h>

// ---------- types ----------
typedef __bf16 vbf8 __attribute__((ext_vector_type(8)));
typedef __bf16 vbf4 __attribute__((ext_vector_type(4)));
typedef unsigned short us8 __attribute__((ext_vector_type(8)));
typedef float f32x4 __attribute__((ext_vector_type(4)));
typedef float f32x4u __attribute__((ext_vector_type(4), aligned(4)));

#define NBLK 64

// ---------- band-case helpers ----------
__device__ __forceinline__ int caseof(int h, int H, int e) {
  if (h < 0 || h >= H) return -1;           // EDGE
  if (h < e) return h;
  if (h >= H - e) return h - (H - 1) + 2 * e;
  return e;
}
__device__ __forceinline__ int repof(int i, int H, int eo) {
  return (i <= eo) ? i : H - 1 - 2 * eo + i;
}

// ---------- device-scope grid barrier (two-phase, generation counter) ----------
__device__ __forceinline__ void gridbar(int* bar) {
  __syncthreads();
  if (threadIdx.x == 0) {
    __threadfence();
    int* cnt = bar; int* gen = bar + 1;
    int g = __hip_atomic_load(gen, __ATOMIC_ACQUIRE, __HIP_MEMORY_SCOPE_AGENT);
    if (__hip_atomic_fetch_add(cnt, 1, __ATOMIC_ACQ_REL, __HIP_MEMORY_SCOPE_AGENT) == NBLK - 1) {
      __hip_atomic_store(cnt, 0, __ATOMIC_RELAXED, __HIP_MEMORY_SCOPE_AGENT);
      __hip_atomic_fetch_add(gen, 1, __ATOMIC_ACQ_REL, __HIP_MEMORY_SCOPE_AGENT);
    } else {
      while (__hip_atomic_load(gen, __ATOMIC_ACQUIRE, __HIP_MEMORY_SCOPE_AGENT) == g)
        __builtin_amdgcn_s_sleep(2);
    }
    __threadfence();
  }
  __syncthreads();
}

// ---------------------------------------------------------------------------
// setup: precompute MFMA weight fragments for the pillar net.
// ---------------------------------------------------------------------------
__global__ void setup_kernel(const float* __restrict__ w1, const float* __restrict__ b1,
                             const float* __restrict__ s1, const float* __restrict__ t1,
                             const float* __restrict__ w2, const float* __restrict__ b2,
                             const float* __restrict__ s2, const float* __restrict__ t2,
                             __bf16* __restrict__ wfrag, float* __restrict__ be2f) {
  int l = threadIdx.x;                       // 0..63
  int s = l & 15, g = l >> 4;
#pragma unroll
  for (int m = 0; m < 4; ++m) {
    int c = 32 * (m & 1) + 8 * (s >> 2) + 4 * (m >> 1) + (s & 3);
#pragma unroll
    for (int e = 0; e < 8; ++e) {
      int k = g * 8 + e;
      float v = 0.f;
      if (k < 9)       v = w1[k * 64 + c] * s1[c];
      else if (k == 9) v = fmaf(b1[c], s1[c], t1[c]);
      wfrag[(m * 64 + l) * 8 + e] = (__bf16)v;
    }
    int co = s + 16 * m;
#pragma unroll
    for (int e = 0; e < 8; ++e) {
      int k = g * 8 + e;
      wfrag[((4 + m) * 64 + l) * 8 + e] = (__bf16)(w2[k * 64 + co] * s2[co]);
      wfrag[((8 + m) * 64 + l) * 8 + e] = (__bf16)(w2[(32 + k) * 64 + co] * s2[co]);
    }
    be2f[m * 64 + l] = fmaf(b2[co], s2[co], t2[co]);
  }
}

// ---------------------------------------------------------------------------
// weight transpose+convert, LDS-tiled: HWIO [tap][ci][co] f32 -> [tap][co][ci] bf16
// ---------------------------------------------------------------------------
__global__ __launch_bounds__(256) void convw_kernel(
    const float* __restrict__ k1, const float* __restrict__ k2,
    const float* __restrict__ k3, const float* __restrict__ k4,
    const float* __restrict__ k5, const float* __restrict__ k6,
    const float* __restrict__ kh, __bf16* __restrict__ wT) {
  __shared__ float tile[64][65];
  const int tCI[7]    = {64, 64, 64, 128, 128, 256, 256};
  const int tCO[7]    = {64, 64, 128, 128, 256, 256, 256};
  const int tOFF[7]   = {0, 36864, 73728, 147456, 294912, 589824, 1179648};
  const int tTILES[7] = {9, 9, 18, 36, 72, 144, 144};
  int bid = blockIdx.x;
  int ti = 0, acc = 0;
  while (ti < 6 && bid >= acc + tTILES[ti]) { acc += tTILES[ti]; ++ti; }
  int lt = bid - acc;
  int CI = tCI[ti], CO = tCO[ti];
  const float* src;
  if (ti == 0) src = k1; else if (ti == 1) src = k2; else if (ti == 2) src = k3;
  else if (ti == 3) src = k4; else if (ti == 4) src = k5; else if (ti == 5) src = k6;
  else src = kh;
  int cot = CO / 64, tpt = (CI / 64) * cot;
  int tap = lt / tpt; int r2 = lt - tap * tpt;
  int ci0 = (r2 / cot) * 64, co0 = (r2 % cot) * 64;
  const float* sp = src + (size_t)(tap * CI + ci0) * CO + co0;
  int t = threadIdx.x;
  int lr = t >> 6, lc = t & 63;
#pragma unroll
  for (int rr = 0; rr < 64; rr += 4)
    tile[rr + lr][lc] = sp[(size_t)(rr + lr) * CO + lc];
  __syncthreads();
  __bf16* dst = wT + tOFF[ti] + ((size_t)tap * CO + co0) * CI + ci0;
#pragma unroll
  for (int rr = 0; rr < 64; rr += 4)
    dst[(size_t)(rr + lr) * CI + lc] = (__bf16)tile[lc][rr + lr];
}

// ---------------------------------------------------------------------------
// Stage A: pillar feature net (unchanged — known-good, ~118 us).
// ---------------------------------------------------------------------------
__global__ __launch_bounds__(256) void pillar_kernel(
    const float* __restrict__ pil, const int* __restrict__ npt,
    const __bf16* __restrict__ wfrag, const float* __restrict__ be2f,
    float* __restrict__ partial, int* __restrict__ pcnt)
{
  __shared__ float redf[4][64];
  __shared__ int redc[4];
  const int tid = threadIdx.x;
  const int wv = tid >> 6, lane = tid & 63;
  const int s = lane & 15, g = lane >> 4;
  const int wid = blockIdx.x * 4 + wv;       // 0..23999
  const int b = wid / 6000;
  const int p0 = (wid - b * 6000) * 2;

  vbf8 w1f[4], w2f0[4], w2f1[4];
  float be2[4];
#pragma unroll
  for (int m = 0; m < 4; ++m) {
    w1f[m]  = *(const vbf8*)(wfrag + ((0 + m) * 64 + lane) * 8);
    w2f0[m] = *(const vbf8*)(wfrag + ((4 + m) * 64 + lane) * 8);
    w2f1[m] = *(const vbf8*)(wfrag + ((8 + m) * 64 + lane) * 8);
    be2[m] = be2f[m * 64 + lane];
  }

  float fsum[4] = {0.f, 0.f, 0.f, 0.f};
  int cnt = 0;

  for (int i = 0; i < 2; ++i) {
    int pidx = b * 12000 + p0 + i;
    int np = npt[pidx];
    if (np <= 0) continue;     // wave-uniform
    ++cnt;
    float feat[4][4];
#pragma unroll
    for (int n = 0; n < 4; ++n)
#pragma unroll
      for (int r = 0; r < 4; ++r) feat[n][r] = 0.f;

    int ngrp = (np + 15) >> 4;
    const float* pbase = pil + (size_t)pidx * 900;
    for (int grp = 0; grp < ngrp; ++grp) {
      int pt = grp * 16 + s; pt = min(pt, 99);
      const float* ptp = pbase + pt * 9;
      f32x4u lo = *(const f32x4u*)ptp;
      f32x4u hi = *(const f32x4u*)(ptp + 4);
      float v8 = ptp[8];
      vbf8 b1f;
      b1f[0] = (__bf16)(g == 0 ? lo[0] : (g == 1 ? v8 : 0.f));
      b1f[1] = (__bf16)(g == 0 ? lo[1] : (g == 1 ? 1.0f : 0.f));
      b1f[2] = (__bf16)(g == 0 ? lo[2] : 0.f);
      b1f[3] = (__bf16)(g == 0 ? lo[3] : 0.f);
      b1f[4] = (__bf16)(g == 0 ? hi[0] : 0.f);
      b1f[5] = (__bf16)(g == 0 ? hi[1] : 0.f);
      b1f[6] = (__bf16)(g == 0 ? hi[2] : 0.f);
      b1f[7] = (__bf16)(g == 0 ? hi[3] : 0.f);

      const f32x4 z = {0.f, 0.f, 0.f, 0.f};
      f32x4 d1[4];
#pragma unroll
      for (int m = 0; m < 4; ++m)
        d1[m] = __builtin_amdgcn_mfma_f32_16x16x32_bf16(w1f[m], b1f, z, 0, 0, 0);

      vbf8 a2f0, a2f1;
#pragma unroll
      for (int r = 0; r < 4; ++r) {
        a2f0[r]     = (__bf16)fmaxf(d1[0][r], 0.f);
        a2f1[r]     = (__bf16)fmaxf(d1[1][r], 0.f);
        a2f0[4 + r] = (__bf16)fmaxf(d1[2][r], 0.f);
        a2f1[4 + r] = (__bf16)fmaxf(d1[3][r], 0.f);
      }

      f32x4 d2[4];
#pragma unroll
      for (int n = 0; n < 4; ++n) {
        f32x4 cb = {be2[n], be2[n], be2[n], be2[n]};
        d2[n] = __builtin_amdgcn_mfma_f32_16x16x32_bf16(a2f0, w2f0[n], cb, 0, 0, 0);
        d2[n] = __builtin_amdgcn_mfma_f32_16x16x32_bf16(a2f1, w2f1[n], d2[n], 0, 0, 0);
      }
      if (((grp + 1) << 4) <= np) {
#pragma unroll
        for (int n = 0; n < 4; ++n)
#pragma unroll
          for (int r = 0; r < 4; ++r) feat[n][r] = fmaxf(feat[n][r], d2[n][r]);
      } else {
#pragma unroll
        for (int n = 0; n < 4; ++n)
#pragma unroll
          for (int r = 0; r < 4; ++r) {
            float vv = (grp * 16 + 4 * g + r < np) ? d2[n][r] : 0.f;
            feat[n][r] = fmaxf(feat[n][r], vv);
          }
      }
    }
#pragma unroll
    for (int n = 0; n < 4; ++n) {
      float m = fmaxf(fmaxf(feat[n][0], feat[n][1]), fmaxf(feat[n][2], feat[n][3]));
      m = fmaxf(m, __shfl_xor(m, 16));
      m = fmaxf(m, __shfl_xor(m, 32));
      fsum[n] += m;
    }
  }
  if (g == 0) {
#pragma unroll
    for (int n = 0; n < 4; ++n) redf[wv][s + 16 * n] = fsum[n];
  }
  if (lane == 0) redc[wv] = cnt;
  __syncthreads();
  if (tid < 64) {
    float tot = redf[0][tid] + redf[1][tid] + redf[2][tid] + redf[3][tid];
    partial[blockIdx.x * 64 + tid] = tot;
    if (tid == 0) pcnt[blockIdx.x] = redc[0] + redc[1] + redc[2] + redc[3];
  }
}

// finish mean + emit X0 + zero zbuf page + zero grid barrier state
__global__ void mean_kernel(const float* __restrict__ partial,
                            const int* __restrict__ pcnt,
                            __bf16* __restrict__ x0,
                            __bf16* __restrict__ zbuf, int* __restrict__ bar) {
  int b = blockIdx.x, t = threadIdx.x;
  if (b == 0) {
    zbuf[t] = (__bf16)0.f;
    if (t < 2) bar[t] = 0;
  }
  int c = t & 63, q = t >> 6;
  float sum = 0.f;
  for (int w = q; w < 1500; w += 4) sum += partial[(b * 1500 + w) * 64 + c];
  int cl = 0;
  for (int w = t; w < 1500; w += 256) cl += pcnt[b * 1500 + w];
  __shared__ float sh[256];
  __shared__ int shc[256];
  sh[t] = sum; shc[t] = cl;
  __syncthreads();
  for (int o = 128; o > 0; o >>= 1) {
    if (t < o) shc[t] += shc[t + o];
    __syncthreads();
  }
  if (t < 64) {
    float tot = sh[t] + sh[t + 64] + sh[t + 128] + sh[t + 192];
    x0[b * 64 + t] = (__bf16)(tot / (float)(shc[0] > 0 ? shc[0] : 1));
  }
}

// ---------------------------------------------------------------------------
// Case-grid conv as a device function (wave-task = 32-row m-tile x 16-col n-tile)
// ---------------------------------------------------------------------------
template <int CI, int CO, int H, int EIN, bool HAS_BN, bool OUT_F32>
__device__ __forceinline__ void caseconv_dev(
    int wid, const __bf16* __restrict__ xin, const __bf16* __restrict__ wt,
    const float* __restrict__ cb, const float* __restrict__ cs,
    const float* __restrict__ ct, __bf16* __restrict__ yout,
    float* __restrict__ yf32, const __bf16* __restrict__ zbuf)
{
  constexpr int EOUT = EIN + 1;
  constexpr int NBI = 2 * EIN + 1;
  constexpr int NBO = 2 * EOUT + 1;
  constexpr int M = NBO * NBO * 4;
  constexpr int NT = CO / 16;
  constexpr int KC = CI / 32;
  constexpr int MT = (M + 31) / 32;
  if (wid >= MT * NT) return;
  const int lane = threadIdx.x & 63;
  const int s = lane & 15, g = lane >> 4;
  const int nt = wid % NT, mt = wid / NT;

  const __bf16* pa[2][9];
#pragma unroll
  for (int mf = 0; mf < 2; ++mf) {
    int m = mt * 32 + mf * 16 + s; if (m >= M) m = M - 1;
    int b = m & 3, q = m >> 2;
    int bw = q % NBO, bh = q / NBO;
    int reph = repof(bh, H, EOUT), repw = repof(bw, H, EOUT);
#pragma unroll
    for (int dh = 0; dh < 3; ++dh)
#pragma unroll
      for (int dw = 0; dw < 3; ++dw) {
        int jh = caseof(reph + dh - 1, H, EIN);
        int jw = caseof(repw + dw - 1, H, EIN);
        bool v = (jh >= 0) && (jw >= 0);
        pa[mf][dh * 3 + dw] =
            v ? xin + (size_t)((jh * NBI + jw) * 4 + b) * CI : zbuf;
      }
  }

  f32x4 acc0 = {0.f, 0.f, 0.f, 0.f}, acc1 = {0.f, 0.f, 0.f, 0.f};
#pragma unroll
  for (int tap = 0; tap < 9; ++tap) {
    const __bf16* wtap = wt + ((size_t)tap * CO + nt * 16) * CI + 8 * g;
#pragma unroll
    for (int ck = 0; ck < KC; ++ck) {
      vbf8 a0 = *(const vbf8*)(pa[0][tap] + ck * 32 + 8 * g);
      vbf8 a1 = *(const vbf8*)(pa[1][tap] + ck * 32 + 8 * g);
      vbf8 bb = *(const vbf8*)(wtap + (size_t)s * CI + ck * 32);
      acc0 = __builtin_amdgcn_mfma_f32_16x16x32_bf16(a0, bb, acc0, 0, 0, 0);
      acc1 = __builtin_amdgcn_mfma_f32_16x16x32_bf16(a1, bb, acc1, 0, 0, 0);
    }
  }

  int co = nt * 16 + s;
  float sc, sh;
  if (HAS_BN) { sc = cs[co]; sh = fmaf(cb[co], sc, ct[co]); }
  else        { sc = 1.f;    sh = cb[co]; }
#pragma unroll
  for (int mf = 0; mf < 2; ++mf) {
    f32x4 acc = mf ? acc1 : acc0;
#pragma unroll
    for (int r = 0; r < 4; ++r) {
      int m = mt * 32 + mf * 16 + 4 * g + r;
      if (m < M) {
        float v = fmaxf(fmaf(acc[r], sc, sh), 0.f);
        if constexpr (OUT_F32) yf32[(size_t)m * CO + co] = v;
        else                   yout[(size_t)m * CO + co] = (__bf16)v;
      }
    }
  }
}

// case-grid 2x2 max pool (device fn, grid-stride over all threads)
template <int C, int HOUT, int EIN>
__device__ __forceinline__ void casepool_dev(int gtid, const __bf16* __restrict__ xin,
                                             __bf16* __restrict__ yout) {
  constexpr int EOUT = (EIN + 1) / 2;
  constexpr int NBI = 2 * EIN + 1;
  constexpr int NBO = 2 * EOUT + 1;
  constexpr int C8 = C / 8;
  for (int idx = gtid; idx < NBO * NBO * 4 * C8; idx += NBLK * 256) {
    int c8 = idx % C8; int rest = idx / C8;
    int b = rest & 3; int pos = rest >> 2;
    int iw = pos % NBO, ih = pos / NBO;
    int rh = repof(ih, HOUT, EOUT), rw = repof(iw, HOUT, EOUT);
    int h0 = caseof(2 * rh, 2 * HOUT, EIN), h1 = caseof(2 * rh + 1, 2 * HOUT, EIN);
    int w0 = caseof(2 * rw, 2 * HOUT, EIN), w1 = caseof(2 * rw + 1, 2 * HOUT, EIN);
    const unsigned short* xp = (const unsigned short*)xin;
    us8 v00 = *(const us8*)(xp + (size_t)((h0 * NBI + w0) * 4 + b) * C + c8 * 8);
    us8 v01 = *(const us8*)(xp + (size_t)((h0 * NBI + w1) * 4 + b) * C + c8 * 8);
    us8 v10 = *(const us8*)(xp + (size_t)((h1 * NBI + w0) * 4 + b) * C + c8 * 8);
    us8 v11 = *(const us8*)(xp + (size_t)((h1 * NBI + w1) * 4 + b) * C + c8 * 8);
    us8 o;
#pragma unroll
    for (int e = 0; e < 8; ++e) {
      unsigned short a = v00[e] > v01[e] ? v00[e] : v01[e];
      unsigned short c = v10[e] > v11[e] ? v10[e] : v11[e];
      o[e] = a > c ? a : c;
    }
    *(us8*)((unsigned short*)yout + (size_t)((ih * NBO + iw) * 4 + b) * C + c8 * 8) = o;
  }
}

__device__ __forceinline__ void head2c_dev(int gtid, const float* __restrict__ x,
                                           const float* __restrict__ wk,
                                           const float* __restrict__ bias,
                                           float* __restrict__ y) {
  for (int idx = gtid; idx < 121 * 4 * 16; idx += NBLK * 256) {
    int co = idx & 15;
    if (co >= 10) continue;
    int q = idx >> 4;
    const float* xr = x + (size_t)q * 256;
    float acc = 0.f;
#pragma unroll 4
    for (int ci = 0; ci < 256; ci += 4) {
      float4 in4 = *(const float4*)(xr + ci);
      acc = fmaf(in4.x, wk[(ci + 0) * 10 + co], acc);
      acc = fmaf(in4.y, wk[(ci + 1) * 10 + co], acc);
      acc = fmaf(in4.z, wk[(ci + 2) * 10 + co], acc);
      acc = fmaf(in4.w, wk[(ci + 3) * 10 + co], acc);
    }
    y[(size_t)q * 10 + co] = acc + bias[co];
  }
}

__device__ __forceinline__ void scatter_dev(int gtid, const float* __restrict__ y,
                                            float* __restrict__ out) {
  for (int idx = gtid; idx < 4 * 10 * 27 * 31; idx += NBLK * 256) {
    int c = idx % 31;
    int r = (idx / 31) % 27;
    int ch = (idx / (31 * 27)) % 10;
    int b = idx / (31 * 27 * 10);
    int rr = (r <= 7) ? r : ((r >= 20) ? r - 11 : 7);
    int cc = (c <= 7) ? c : ((c >= 24) ? c - 15 : 7);
    int ph = caseof(rr, 16, 5), pw = caseof(cc, 16, 5);
    out[idx] = y[(size_t)(((ph * 11 + pw) * 4 + b)) * 10 + ch];
  }
}

// ---------------------------------------------------------------------------
// fused backbone: 7 caseconvs + 2 pools + head2 + scatter, grid barriers between
// ---------------------------------------------------------------------------
__global__ __launch_bounds__(256) void backbone_kernel(
    const __bf16* __restrict__ X0, __bf16* __restrict__ X1, __bf16* __restrict__ X2,
    __bf16* __restrict__ P1, __bf16* __restrict__ X3, __bf16* __restrict__ X4,
    __bf16* __restrict__ P2, __bf16* __restrict__ X5, __bf16* __restrict__ X6,
    float* __restrict__ XH, float* __restrict__ h2out,
    const __bf16* wt1, const __bf16* wt2, const __bf16* wt3, const __bf16* wt4,
    const __bf16* wt5, const __bf16* wt6, const __bf16* wth,
    const float* cb1, const float* cs1, const float* ct1,
    const float* cb2, const float* cs2, const float* ct2,
    const float* cb3, const float* cs3, const float* ct3,
    const float* cb4, const float* cs4, const float* ct4,
    const float* cb5, const float* cs5, const float* ct5,
    const float* cb6, const float* cs6, const float* ct6,
    const float* hb1, const float* hk2, const float* hb2,
    const __bf16* __restrict__ zbuf, int* __restrict__ bar, float* __restrict__ out)
{
  const int wid = blockIdx.x * 4 + (threadIdx.x >> 6);
  const int gtid = blockIdx.x * 256 + threadIdx.x;

  caseconv_dev<64, 64, 64, 0, true, false>(wid, X0, wt1, cb1, cs1, ct1, X1, nullptr, zbuf);
  gridbar(bar);
  caseconv_dev<64, 64, 64, 1, true, false>(wid, X1, wt2, cb2, cs2, ct2, X2, nullptr, zbuf);
  gridbar(bar);
  casepool_dev<64, 32, 2>(gtid, X2, P1);
  gridbar(bar);
  caseconv_dev<64, 128, 32, 1, true, false>(wid, P1, wt3, cb3, cs3, ct3, X3, nullptr, zbuf);
  gridbar(bar);
  caseconv_dev<128, 128, 32, 2, true, false>(wid, X3, wt4, cb4, cs4, ct4, X4, nullptr, zbuf);
  gridbar(bar);
  casepool_dev<128, 16, 3>(gtid, X4, P2);
  gridbar(bar);
  caseconv_dev<128, 256, 16, 2, true, false>(wid, P2, wt5, cb5, cs5, ct5, X5, nullptr, zbuf);
  gridbar(bar);
  caseconv_dev<256, 256, 16, 3, true, false>(wid, X5, wt6, cb6, cs6, ct6, X6, nullptr, zbuf);
  gridbar(bar);
  caseconv_dev<256, 256, 16, 4, false, true>(wid, X6, wth, hb1, nullptr, nullptr, nullptr, XH, zbuf);
  gridbar(bar);
  head2c_dev(gtid, XH, hk2, hb2, h2out);
  gridbar(bar);
  scatter_dev(gtid, h2out, out);
}

// ---------------------------------------------------------------------------
extern "C" void kernel_launch(void* const* d_in, const int* in_sizes, int n_in,
                              void* d_out, int out_size, void* d_ws, size_t ws_size,
                              hipStream_t stream) {
  (void)in_sizes; (void)n_in; (void)out_size; (void)ws_size;
  const float* pillars = (const float*)d_in[0];
  const float* w1 = (const float*)d_in[1];
  const float* b1 = (const float*)d_in[2];
  const float* s1 = (const float*)d_in[3];
  const float* t1 = (const float*)d_in[4];
  const float* w2 = (const float*)d_in[5];
  const float* b2 = (const float*)d_in[6];
  const float* s2 = (const float*)d_in[7];
  const float* t2 = (const float*)d_in[8];
  const float* ck[6], *cbv[6], *csv[6], *ctv[6];
  for (int i = 0; i < 6; ++i) {
    ck[i]  = (const float*)d_in[9 + i * 4];
    cbv[i] = (const float*)d_in[10 + i * 4];
    csv[i] = (const float*)d_in[11 + i * 4];
    ctv[i] = (const float*)d_in[12 + i * 4];
  }
  const float* hk1 = (const float*)d_in[33];
  const float* hb1 = (const float*)d_in[34];
  const float* hk2 = (const float*)d_in[35];
  const float* hb2 = (const float*)d_in[36];
  const int* num_points = (const int*)d_in[37];
  float* out = (float*)d_out;

  // ---- ws layout ----
  char* wsb = (char*)d_ws;
  size_t off = 0;
  auto alloc = [&](size_t n) { char* p = wsb + off; off = (off + n + 255) & ~(size_t)255; return p; };
  float*  ppart = (float*)alloc(1536000);
  int*    pcnt  = (int*)alloc(24000);
  __bf16* wfrag = (__bf16*)alloc(12288);
  float*  be2f  = (float*)alloc(1024);
  __bf16* wT    = (__bf16*)alloc(3538944);
  __bf16* zbuf  = (__bf16*)alloc(512);
  int*    bar   = (int*)alloc(256);
  __bf16* X0    = (__bf16*)alloc(512);       // 1x1x4x64
  __bf16* X1    = (__bf16*)alloc(4608);      // 3x3x4x64
  __bf16* X2    = (__bf16*)alloc(12800);     // 5x5x4x64
  __bf16* P1    = (__bf16*)alloc(4608);      // 3x3x4x64
  __bf16* X3    = (__bf16*)alloc(25600);     // 5x5x4x128
  __bf16* X4    = (__bf16*)alloc(50176);     // 7x7x4x128
  __bf16* P2    = (__bf16*)alloc(25600);     // 5x5x4x128
  __bf16* X5    = (__bf16*)alloc(100352);    // 7x7x4x256
  __bf16* X6    = (__bf16*)alloc(165888);    // 9x9x4x256
  float*  XH    = (float*)alloc(495616);     // 11x11x4x256 f32
  float*  h2out = (float*)alloc(19360);      // 11x11x4x10

  __bf16* wt1 = wT + 0;       __bf16* wt2 = wT + 36864;
  __bf16* wt3 = wT + 73728;   __bf16* wt4 = wT + 147456;
  __bf16* wt5 = wT + 294912;  __bf16* wt6 = wT + 589824;
  __bf16* wth = wT + 1179648;

  setup_kernel<<<1, 64, 0, stream>>>(w1, b1, s1, t1, w2, b2, s2, t2, wfrag, be2f);
  convw_kernel<<<432, 256, 0, stream>>>(ck[0], ck[1], ck[2], ck[3], ck[4], ck[5],
                                        hk1, wT);
  pillar_kernel<<<6000, 256, 0, stream>>>(pillars, num_points, wfrag, be2f,
                                          ppart, pcnt);
  mean_kernel<<<4, 256, 0, stream>>>(ppart, pcnt, X0, zbuf, bar);
  backbone_kernel<<<NBLK, 256, 0, stream>>>(
      X0, X1, X2, P1, X3, X4, P2, X5, X6, XH, h2out,
      wt1, wt2, wt3, wt4, wt5, wt6, wth,
      cbv[0], csv[0], ctv[0], cbv[1], csv[1], ctv[1],
      cbv[2], csv[2], ctv[2], cbv[3], csv[3], ctv[3],
      cbv[4], csv[4], ctv[4], cbv[5], csv[5], ctv[5],
      hb1, hk2, hb2, zbuf, bar, out);
}

// Round 8
// 332.647 us; speedup vs baseline: 1.3168x; 1.1080x over previous
//
#include <hip/hip_runtime.h>

// ---------- types ----------
typedef __bf16 vbf8 __attribute__((ext_vector_type(8)));
typedef __bf16 vbf4 __attribute__((ext_vector_type(4)));
typedef unsigned short us8 __attribute__((ext_vector_type(8)));
typedef float f32x4 __attribute__((ext_vector_type(4)));
typedef float f32x4u __attribute__((ext_vector_type(4), aligned(4)));

#define NBLK 64

// ---------- band-case helpers ----------
__device__ __forceinline__ int caseof(int h, int H, int e) {
  if (h < 0 || h >= H) return -1;           // EDGE
  if (h < e) return h;
  if (h >= H - e) return h - (H - 1) + 2 * e;
  return e;
}
__device__ __forceinline__ int repof(int i, int H, int eo) {
  return (i <= eo) ? i : H - 1 - 2 * eo + i;
}

// ---------- device-scope grid barrier ----------
// RELAXED polling (no per-poll cache invalidation!) + single acquire fence
// after the generation flip is observed. Winner's ACQ_REL RMW provides its
// own release/acquire. State (cnt, gen) is zeroed by mean_kernel every call.
__device__ __forceinline__ void gridbar(int* bar) {
  __syncthreads();
  if (threadIdx.x == 0) {
    int* cnt = bar; int* gen = bar + 1;
    int g = __hip_atomic_load(gen, __ATOMIC_RELAXED, __HIP_MEMORY_SCOPE_AGENT);
    if (__hip_atomic_fetch_add(cnt, 1, __ATOMIC_ACQ_REL, __HIP_MEMORY_SCOPE_AGENT) == NBLK - 1) {
      __hip_atomic_store(cnt, 0, __ATOMIC_RELAXED, __HIP_MEMORY_SCOPE_AGENT);
      __hip_atomic_store(gen, g + 1, __ATOMIC_RELEASE, __HIP_MEMORY_SCOPE_AGENT);
    } else {
      while (__hip_atomic_load(gen, __ATOMIC_RELAXED, __HIP_MEMORY_SCOPE_AGENT) == g)
        __builtin_amdgcn_s_sleep(8);
      __threadfence();                      // one acquire: invalidate stale caches
    }
  }
  __syncthreads();
}

// ---------------------------------------------------------------------------
// setup: precompute MFMA weight fragments for the pillar net.
// ---------------------------------------------------------------------------
__global__ void setup_kernel(const float* __restrict__ w1, const float* __restrict__ b1,
                             const float* __restrict__ s1, const float* __restrict__ t1,
                             const float* __restrict__ w2, const float* __restrict__ b2,
                             const float* __restrict__ s2, const float* __restrict__ t2,
                             __bf16* __restrict__ wfrag, float* __restrict__ be2f) {
  int l = threadIdx.x;                       // 0..63
  int s = l & 15, g = l >> 4;
#pragma unroll
  for (int m = 0; m < 4; ++m) {
    int c = 32 * (m & 1) + 8 * (s >> 2) + 4 * (m >> 1) + (s & 3);
#pragma unroll
    for (int e = 0; e < 8; ++e) {
      int k = g * 8 + e;
      float v = 0.f;
      if (k < 9)       v = w1[k * 64 + c] * s1[c];
      else if (k == 9) v = fmaf(b1[c], s1[c], t1[c]);
      wfrag[(m * 64 + l) * 8 + e] = (__bf16)v;
    }
    int co = s + 16 * m;
#pragma unroll
    for (int e = 0; e < 8; ++e) {
      int k = g * 8 + e;
      wfrag[((4 + m) * 64 + l) * 8 + e] = (__bf16)(w2[k * 64 + co] * s2[co]);
      wfrag[((8 + m) * 64 + l) * 8 + e] = (__bf16)(w2[(32 + k) * 64 + co] * s2[co]);
    }
    be2f[m * 64 + l] = fmaf(b2[co], s2[co], t2[co]);
  }
}

// ---------------------------------------------------------------------------
// weight transpose+convert, LDS-tiled: HWIO [tap][ci][co] f32 -> [tap][co][ci] bf16
// ---------------------------------------------------------------------------
__global__ __launch_bounds__(256) void convw_kernel(
    const float* __restrict__ k1, const float* __restrict__ k2,
    const float* __restrict__ k3, const float* __restrict__ k4,
    const float* __restrict__ k5, const float* __restrict__ k6,
    const float* __restrict__ kh, __bf16* __restrict__ wT) {
  __shared__ float tile[64][65];
  const int tCI[7]    = {64, 64, 64, 128, 128, 256, 256};
  const int tCO[7]    = {64, 64, 128, 128, 256, 256, 256};
  const int tOFF[7]   = {0, 36864, 73728, 147456, 294912, 589824, 1179648};
  const int tTILES[7] = {9, 9, 18, 36, 72, 144, 144};
  int bid = blockIdx.x;
  int ti = 0, acc = 0;
  while (ti < 6 && bid >= acc + tTILES[ti]) { acc += tTILES[ti]; ++ti; }
  int lt = bid - acc;
  int CI = tCI[ti], CO = tCO[ti];
  const float* src;
  if (ti == 0) src = k1; else if (ti == 1) src = k2; else if (ti == 2) src = k3;
  else if (ti == 3) src = k4; else if (ti == 4) src = k5; else if (ti == 5) src = k6;
  else src = kh;
  int cot = CO / 64, tpt = (CI / 64) * cot;
  int tap = lt / tpt; int r2 = lt - tap * tpt;
  int ci0 = (r2 / cot) * 64, co0 = (r2 % cot) * 64;
  const float* sp = src + (size_t)(tap * CI + ci0) * CO + co0;
  int t = threadIdx.x;
  int lr = t >> 6, lc = t & 63;
#pragma unroll
  for (int rr = 0; rr < 64; rr += 4)
    tile[rr + lr][lc] = sp[(size_t)(rr + lr) * CO + lc];
  __syncthreads();
  __bf16* dst = wT + tOFF[ti] + ((size_t)tap * CO + co0) * CI + ci0;
#pragma unroll
  for (int rr = 0; rr < 64; rr += 4)
    dst[(size_t)(rr + lr) * CI + lc] = (__bf16)tile[lc][rr + lr];
}

// ---------------------------------------------------------------------------
// Stage A: pillar feature net, 1-deep group software pipeline.
// ---------------------------------------------------------------------------
__global__ __launch_bounds__(256) void pillar_kernel(
    const float* __restrict__ pil, const int* __restrict__ npt,
    const __bf16* __restrict__ wfrag, const float* __restrict__ be2f,
    float* __restrict__ partial, int* __restrict__ pcnt)
{
  __shared__ float redf[4][64];
  __shared__ int redc[4];
  const int tid = threadIdx.x;
  const int wv = tid >> 6, lane = tid & 63;
  const int s = lane & 15, g = lane >> 4;
  const int wid = blockIdx.x * 4 + wv;       // 0..23999
  const int b = wid / 6000;
  const int p0 = (wid - b * 6000) * 2;

  vbf8 w1f[4], w2f0[4], w2f1[4];
  float be2[4];
#pragma unroll
  for (int m = 0; m < 4; ++m) {
    w1f[m]  = *(const vbf8*)(wfrag + ((0 + m) * 64 + lane) * 8);
    w2f0[m] = *(const vbf8*)(wfrag + ((4 + m) * 64 + lane) * 8);
    w2f1[m] = *(const vbf8*)(wfrag + ((8 + m) * 64 + lane) * 8);
    be2[m] = be2f[m * 64 + lane];
  }

  float fsum[4] = {0.f, 0.f, 0.f, 0.f};
  int cnt = 0;

  for (int i = 0; i < 2; ++i) {
    int pidx = b * 12000 + p0 + i;
    int np = npt[pidx];
    if (np <= 0) continue;     // wave-uniform
    ++cnt;
    float feat[4][4];
#pragma unroll
    for (int n = 0; n < 4; ++n)
#pragma unroll
      for (int r = 0; r < 4; ++r) feat[n][r] = 0.f;

    int ngrp = (np + 15) >> 4;
    const float* pbase = pil + (size_t)pidx * 900;
    // prologue: load group 0 (pt = s <= 15, always in bounds)
    const float* pp0 = pbase + s * 9;
    f32x4u lo = *(const f32x4u*)pp0;
    f32x4u hi = *(const f32x4u*)(pp0 + 4);
    float v8 = pp0[8];
    for (int grp = 0; grp < ngrp; ++grp) {
      // issue next group's loads first (independent of current compute)
      int g2 = min(grp + 1, ngrp - 1);
      int ptn = min(g2 * 16 + s, 99);
      const float* ppn = pbase + ptn * 9;
      f32x4u nlo = *(const f32x4u*)ppn;
      f32x4u nhi = *(const f32x4u*)(ppn + 4);
      float nv8 = ppn[8];

      vbf8 b1f;
      b1f[0] = (__bf16)(g == 0 ? lo[0] : (g == 1 ? v8 : 0.f));
      b1f[1] = (__bf16)(g == 0 ? lo[1] : (g == 1 ? 1.0f : 0.f));
      b1f[2] = (__bf16)(g == 0 ? lo[2] : 0.f);
      b1f[3] = (__bf16)(g == 0 ? lo[3] : 0.f);
      b1f[4] = (__bf16)(g == 0 ? hi[0] : 0.f);
      b1f[5] = (__bf16)(g == 0 ? hi[1] : 0.f);
      b1f[6] = (__bf16)(g == 0 ? hi[2] : 0.f);
      b1f[7] = (__bf16)(g == 0 ? hi[3] : 0.f);

      const f32x4 z = {0.f, 0.f, 0.f, 0.f};
      f32x4 d1[4];
#pragma unroll
      for (int m = 0; m < 4; ++m)
        d1[m] = __builtin_amdgcn_mfma_f32_16x16x32_bf16(w1f[m], b1f, z, 0, 0, 0);

      vbf8 a2f0, a2f1;
#pragma unroll
      for (int r = 0; r < 4; ++r) {
        a2f0[r]     = (__bf16)fmaxf(d1[0][r], 0.f);
        a2f1[r]     = (__bf16)fmaxf(d1[1][r], 0.f);
        a2f0[4 + r] = (__bf16)fmaxf(d1[2][r], 0.f);
        a2f1[4 + r] = (__bf16)fmaxf(d1[3][r], 0.f);
      }

      f32x4 d2[4];
#pragma unroll
      for (int n = 0; n < 4; ++n) {
        f32x4 cb = {be2[n], be2[n], be2[n], be2[n]};
        d2[n] = __builtin_amdgcn_mfma_f32_16x16x32_bf16(a2f0, w2f0[n], cb, 0, 0, 0);
        d2[n] = __builtin_amdgcn_mfma_f32_16x16x32_bf16(a2f1, w2f1[n], d2[n], 0, 0, 0);
      }
      if (((grp + 1) << 4) <= np) {
#pragma unroll
        for (int n = 0; n < 4; ++n)
#pragma unroll
          for (int r = 0; r < 4; ++r) feat[n][r] = fmaxf(feat[n][r], d2[n][r]);
      } else {
#pragma unroll
        for (int n = 0; n < 4; ++n)
#pragma unroll
          for (int r = 0; r < 4; ++r) {
            float vv = (grp * 16 + 4 * g + r < np) ? d2[n][r] : 0.f;
            feat[n][r] = fmaxf(feat[n][r], vv);
          }
      }
      lo = nlo; hi = nhi; v8 = nv8;
    }
#pragma unroll
    for (int n = 0; n < 4; ++n) {
      float m = fmaxf(fmaxf(feat[n][0], feat[n][1]), fmaxf(feat[n][2], feat[n][3]));
      m = fmaxf(m, __shfl_xor(m, 16));
      m = fmaxf(m, __shfl_xor(m, 32));
      fsum[n] += m;
    }
  }
  if (g == 0) {
#pragma unroll
    for (int n = 0; n < 4; ++n) redf[wv][s + 16 * n] = fsum[n];
  }
  if (lane == 0) redc[wv] = cnt;
  __syncthreads();
  if (tid < 64) {
    float tot = redf[0][tid] + redf[1][tid] + redf[2][tid] + redf[3][tid];
    partial[blockIdx.x * 64 + tid] = tot;
    if (tid == 0) pcnt[blockIdx.x] = redc[0] + redc[1] + redc[2] + redc[3];
  }
}

// finish mean + emit X0 + zero zbuf page + zero grid barrier state
__global__ void mean_kernel(const float* __restrict__ partial,
                            const int* __restrict__ pcnt,
                            __bf16* __restrict__ x0,
                            __bf16* __restrict__ zbuf, int* __restrict__ bar) {
  int b = blockIdx.x, t = threadIdx.x;
  if (b == 0) {
    zbuf[t] = (__bf16)0.f;
    if (t < 2) bar[t] = 0;
  }
  int c = t & 63, q = t >> 6;
  float sum = 0.f;
  for (int w = q; w < 1500; w += 4) sum += partial[(b * 1500 + w) * 64 + c];
  int cl = 0;
  for (int w = t; w < 1500; w += 256) cl += pcnt[b * 1500 + w];
  __shared__ float sh[256];
  __shared__ int shc[256];
  sh[t] = sum; shc[t] = cl;
  __syncthreads();
  for (int o = 128; o > 0; o >>= 1) {
    if (t < o) shc[t] += shc[t + o];
    __syncthreads();
  }
  if (t < 64) {
    float tot = sh[t] + sh[t + 64] + sh[t + 128] + sh[t + 192];
    x0[b * 64 + t] = (__bf16)(tot / (float)(shc[0] > 0 ? shc[0] : 1));
  }
}

// ---------------------------------------------------------------------------
// Case-grid conv as a device function (wave-task = 32-row m-tile x 16-col n-tile)
// ---------------------------------------------------------------------------
template <int CI, int CO, int H, int EIN, bool HAS_BN, bool OUT_F32>
__device__ __forceinline__ void caseconv_dev(
    int wid, const __bf16* __restrict__ xin, const __bf16* __restrict__ wt,
    const float* __restrict__ cb, const float* __restrict__ cs,
    const float* __restrict__ ct, __bf16* __restrict__ yout,
    float* __restrict__ yf32, const __bf16* __restrict__ zbuf)
{
  constexpr int EOUT = EIN + 1;
  constexpr int NBI = 2 * EIN + 1;
  constexpr int NBO = 2 * EOUT + 1;
  constexpr int M = NBO * NBO * 4;
  constexpr int NT = CO / 16;
  constexpr int KC = CI / 32;
  constexpr int MT = (M + 31) / 32;
  if (wid >= MT * NT) return;
  const int lane = threadIdx.x & 63;
  const int s = lane & 15, g = lane >> 4;
  const int nt = wid % NT, mt = wid / NT;

  const __bf16* pa[2][9];
#pragma unroll
  for (int mf = 0; mf < 2; ++mf) {
    int m = mt * 32 + mf * 16 + s; if (m >= M) m = M - 1;
    int b = m & 3, q = m >> 2;
    int bw = q % NBO, bh = q / NBO;
    int reph = repof(bh, H, EOUT), repw = repof(bw, H, EOUT);
#pragma unroll
    for (int dh = 0; dh < 3; ++dh)
#pragma unroll
      for (int dw = 0; dw < 3; ++dw) {
        int jh = caseof(reph + dh - 1, H, EIN);
        int jw = caseof(repw + dw - 1, H, EIN);
        bool v = (jh >= 0) && (jw >= 0);
        pa[mf][dh * 3 + dw] =
            v ? xin + (size_t)((jh * NBI + jw) * 4 + b) * CI : zbuf;
      }
  }

  f32x4 acc0 = {0.f, 0.f, 0.f, 0.f}, acc1 = {0.f, 0.f, 0.f, 0.f};
#pragma unroll
  for (int tap = 0; tap < 9; ++tap) {
    const __bf16* wtap = wt + ((size_t)tap * CO + nt * 16) * CI + 8 * g;
#pragma unroll
    for (int ck = 0; ck < KC; ++ck) {
      vbf8 a0 = *(const vbf8*)(pa[0][tap] + ck * 32 + 8 * g);
      vbf8 a1 = *(const vbf8*)(pa[1][tap] + ck * 32 + 8 * g);
      vbf8 bb = *(const vbf8*)(wtap + (size_t)s * CI + ck * 32);
      acc0 = __builtin_amdgcn_mfma_f32_16x16x32_bf16(a0, bb, acc0, 0, 0, 0);
      acc1 = __builtin_amdgcn_mfma_f32_16x16x32_bf16(a1, bb, acc1, 0, 0, 0);
    }
  }

  int co = nt * 16 + s;
  float sc, sh;
  if (HAS_BN) { sc = cs[co]; sh = fmaf(cb[co], sc, ct[co]); }
  else        { sc = 1.f;    sh = cb[co]; }
#pragma unroll
  for (int mf = 0; mf < 2; ++mf) {
    f32x4 acc = mf ? acc1 : acc0;
#pragma unroll
    for (int r = 0; r < 4; ++r) {
      int m = mt * 32 + mf * 16 + 4 * g + r;
      if (m < M) {
        float v = fmaxf(fmaf(acc[r], sc, sh), 0.f);
        if constexpr (OUT_F32) yf32[(size_t)m * CO + co] = v;
        else                   yout[(size_t)m * CO + co] = (__bf16)v;
      }
    }
  }
}

// case-grid 2x2 max pool (device fn, grid-stride over all threads)
template <int C, int HOUT, int EIN>
__device__ __forceinline__ void casepool_dev(int gtid, const __bf16* __restrict__ xin,
                                             __bf16* __restrict__ yout) {
  constexpr int EOUT = (EIN + 1) / 2;
  constexpr int NBI = 2 * EIN + 1;
  constexpr int NBO = 2 * EOUT + 1;
  constexpr int C8 = C / 8;
  for (int idx = gtid; idx < NBO * NBO * 4 * C8; idx += NBLK * 256) {
    int c8 = idx % C8; int rest = idx / C8;
    int b = rest & 3; int pos = rest >> 2;
    int iw = pos % NBO, ih = pos / NBO;
    int rh = repof(ih, HOUT, EOUT), rw = repof(iw, HOUT, EOUT);
    int h0 = caseof(2 * rh, 2 * HOUT, EIN), h1 = caseof(2 * rh + 1, 2 * HOUT, EIN);
    int w0 = caseof(2 * rw, 2 * HOUT, EIN), w1 = caseof(2 * rw + 1, 2 * HOUT, EIN);
    const unsigned short* xp = (const unsigned short*)xin;
    us8 v00 = *(const us8*)(xp + (size_t)((h0 * NBI + w0) * 4 + b) * C + c8 * 8);
    us8 v01 = *(const us8*)(xp + (size_t)((h0 * NBI + w1) * 4 + b) * C + c8 * 8);
    us8 v10 = *(const us8*)(xp + (size_t)((h1 * NBI + w0) * 4 + b) * C + c8 * 8);
    us8 v11 = *(const us8*)(xp + (size_t)((h1 * NBI + w1) * 4 + b) * C + c8 * 8);
    us8 o;
#pragma unroll
    for (int e = 0; e < 8; ++e) {
      unsigned short a = v00[e] > v01[e] ? v00[e] : v01[e];
      unsigned short c = v10[e] > v11[e] ? v10[e] : v11[e];
      o[e] = a > c ? a : c;
    }
    *(us8*)((unsigned short*)yout + (size_t)((ih * NBO + iw) * 4 + b) * C + c8 * 8) = o;
  }
}

__device__ __forceinline__ void head2c_dev(int gtid, const float* __restrict__ x,
                                           const float* __restrict__ wk,
                                           const float* __restrict__ bias,
                                           float* __restrict__ y) {
  for (int idx = gtid; idx < 121 * 4 * 16; idx += NBLK * 256) {
    int co = idx & 15;
    if (co >= 10) continue;
    int q = idx >> 4;
    const float* xr = x + (size_t)q * 256;
    float acc = 0.f;
#pragma unroll 4
    for (int ci = 0; ci < 256; ci += 4) {
      float4 in4 = *(const float4*)(xr + ci);
      acc = fmaf(in4.x, wk[(ci + 0) * 10 + co], acc);
      acc = fmaf(in4.y, wk[(ci + 1) * 10 + co], acc);
      acc = fmaf(in4.z, wk[(ci + 2) * 10 + co], acc);
      acc = fmaf(in4.w, wk[(ci + 3) * 10 + co], acc);
    }
    y[(size_t)q * 10 + co] = acc + bias[co];
  }
}

__device__ __forceinline__ void scatter_dev(int gtid, const float* __restrict__ y,
                                            float* __restrict__ out) {
  for (int idx = gtid; idx < 4 * 10 * 27 * 31; idx += NBLK * 256) {
    int c = idx % 31;
    int r = (idx / 31) % 27;
    int ch = (idx / (31 * 27)) % 10;
    int b = idx / (31 * 27 * 10);
    int rr = (r <= 7) ? r : ((r >= 20) ? r - 11 : 7);
    int cc = (c <= 7) ? c : ((c >= 24) ? c - 15 : 7);
    int ph = caseof(rr, 16, 5), pw = caseof(cc, 16, 5);
    out[idx] = y[(size_t)(((ph * 11 + pw) * 4 + b)) * 10 + ch];
  }
}

// ---------------------------------------------------------------------------
// fused backbone: 7 caseconvs + 2 pools + head2 + scatter, grid barriers between
// ---------------------------------------------------------------------------
__global__ __launch_bounds__(256) void backbone_kernel(
    const __bf16* __restrict__ X0, __bf16* __restrict__ X1, __bf16* __restrict__ X2,
    __bf16* __restrict__ P1, __bf16* __restrict__ X3, __bf16* __restrict__ X4,
    __bf16* __restrict__ P2, __bf16* __restrict__ X5, __bf16* __restrict__ X6,
    float* __restrict__ XH, float* __restrict__ h2out,
    const __bf16* wt1, const __bf16* wt2, const __bf16* wt3, const __bf16* wt4,
    const __bf16* wt5, const __bf16* wt6, const __bf16* wth,
    const float* cb1, const float* cs1, const float* ct1,
    const float* cb2, const float* cs2, const float* ct2,
    const float* cb3, const float* cs3, const float* ct3,
    const float* cb4, const float* cs4, const float* ct4,
    const float* cb5, const float* cs5, const float* ct5,
    const float* cb6, const float* cs6, const float* ct6,
    const float* hb1, const float* hk2, const float* hb2,
    const __bf16* __restrict__ zbuf, int* __restrict__ bar, float* __restrict__ out)
{
  const int wid = blockIdx.x * 4 + (threadIdx.x >> 6);
  const int gtid = blockIdx.x * 256 + threadIdx.x;

  caseconv_dev<64, 64, 64, 0, true, false>(wid, X0, wt1, cb1, cs1, ct1, X1, nullptr, zbuf);
  gridbar(bar);
  caseconv_dev<64, 64, 64, 1, true, false>(wid, X1, wt2, cb2, cs2, ct2, X2, nullptr, zbuf);
  gridbar(bar);
  casepool_dev<64, 32, 2>(gtid, X2, P1);
  gridbar(bar);
  caseconv_dev<64, 128, 32, 1, true, false>(wid, P1, wt3, cb3, cs3, ct3, X3, nullptr, zbuf);
  gridbar(bar);
  caseconv_dev<128, 128, 32, 2, true, false>(wid, X3, wt4, cb4, cs4, ct4, X4, nullptr, zbuf);
  gridbar(bar);
  casepool_dev<128, 16, 3>(gtid, X4, P2);
  gridbar(bar);
  caseconv_dev<128, 256, 16, 2, true, false>(wid, P2, wt5, cb5, cs5, ct5, X5, nullptr, zbuf);
  gridbar(bar);
  caseconv_dev<256, 256, 16, 3, true, false>(wid, X5, wt6, cb6, cs6, ct6, X6, nullptr, zbuf);
  gridbar(bar);
  caseconv_dev<256, 256, 16, 4, false, true>(wid, X6, wth, hb1, nullptr, nullptr, nullptr, XH, zbuf);
  gridbar(bar);
  head2c_dev(gtid, XH, hk2, hb2, h2out);
  gridbar(bar);
  scatter_dev(gtid, h2out, out);
}

// ---------------------------------------------------------------------------
extern "C" void kernel_launch(void* const* d_in, const int* in_sizes, int n_in,
                              void* d_out, int out_size, void* d_ws, size_t ws_size,
                              hipStream_t stream) {
  (void)in_sizes; (void)n_in; (void)out_size; (void)ws_size;
  const float* pillars = (const float*)d_in[0];
  const float* w1 = (const float*)d_in[1];
  const float* b1 = (const float*)d_in[2];
  const float* s1 = (const float*)d_in[3];
  const float* t1 = (const float*)d_in[4];
  const float* w2 = (const float*)d_in[5];
  const float* b2 = (const float*)d_in[6];
  const float* s2 = (const float*)d_in[7];
  const float* t2 = (const float*)d_in[8];
  const float* ck[6], *cbv[6], *csv[6], *ctv[6];
  for (int i = 0; i < 6; ++i) {
    ck[i]  = (const float*)d_in[9 + i * 4];
    cbv[i] = (const float*)d_in[10 + i * 4];
    csv[i] = (const float*)d_in[11 + i * 4];
    ctv[i] = (const float*)d_in[12 + i * 4];
  }
  const float* hk1 = (const float*)d_in[33];
  const float* hb1 = (const float*)d_in[34];
  const float* hk2 = (const float*)d_in[35];
  const float* hb2 = (const float*)d_in[36];
  const int* num_points = (const int*)d_in[37];
  float* out = (float*)d_out;

  // ---- ws layout ----
  char* wsb = (char*)d_ws;
  size_t off = 0;
  auto alloc = [&](size_t n) { char* p = wsb + off; off = (off + n + 255) & ~(size_t)255; return p; };
  float*  ppart = (float*)alloc(1536000);
  int*    pcnt  = (int*)alloc(24000);
  __bf16* wfrag = (__bf16*)alloc(12288);
  float*  be2f  = (float*)alloc(1024);
  __bf16* wT    = (__bf16*)alloc(3538944);
  __bf16* zbuf  = (__bf16*)alloc(512);
  int*    bar   = (int*)alloc(256);
  __bf16* X0    = (__bf16*)alloc(512);       // 1x1x4x64
  __bf16* X1    = (__bf16*)alloc(4608);      // 3x3x4x64
  __bf16* X2    = (__bf16*)alloc(12800);     // 5x5x4x64
  __bf16* P1    = (__bf16*)alloc(4608);      // 3x3x4x64
  __bf16* X3    = (__bf16*)alloc(25600);     // 5x5x4x128
  __bf16* X4    = (__bf16*)alloc(50176);     // 7x7x4x128
  __bf16* P2    = (__bf16*)alloc(25600);     // 5x5x4x128
  __bf16* X5    = (__bf16*)alloc(100352);    // 7x7x4x256
  __bf16* X6    = (__bf16*)alloc(165888);    // 9x9x4x256
  float*  XH    = (float*)alloc(495616);     // 11x11x4x256 f32
  float*  h2out = (float*)alloc(19360);      // 11x11x4x10

  __bf16* wt1 = wT + 0;       __bf16* wt2 = wT + 36864;
  __bf16* wt3 = wT + 73728;   __bf16* wt4 = wT + 147456;
  __bf16* wt5 = wT + 294912;  __bf16* wt6 = wT + 589824;
  __bf16* wth = wT + 1179648;

  setup_kernel<<<1, 64, 0, stream>>>(w1, b1, s1, t1, w2, b2, s2, t2, wfrag, be2f);
  convw_kernel<<<432, 256, 0, stream>>>(ck[0], ck[1], ck[2], ck[3], ck[4], ck[5],
                                        hk1, wT);
  pillar_kernel<<<6000, 256, 0, stream>>>(pillars, num_points, wfrag, be2f,
                                          ppart, pcnt);
  mean_kernel<<<4, 256, 0, stream>>>(ppart, pcnt, X0, zbuf, bar);
  backbone_kernel<<<NBLK, 256, 0, stream>>>(
      X0, X1, X2, P1, X3, X4, P2, X5, X6, XH, h2out,
      wt1, wt2, wt3, wt4, wt5, wt6, wth,
      cbv[0], csv[0], ctv[0], cbv[1], csv[1], ctv[1],
      cbv[2], csv[2], ctv[2], cbv[3], csv[3], ctv[3],
      cbv[4], csv[4], ctv[4], cbv[5], csv[5], ctv[5],
      hb1, hk2, hb2, zbuf, bar, out);
}